// Round 1
// baseline (96.325 us; speedup 1.0000x reference)
//
#include <hip/hip_runtime.h>
#include <math.h>

#define NQ  12
#define DIM 4096

// ---------------------------------------------------------------------------
// Kernel A: v_b = U_params^dagger e_b  for b in {0,1}.  One block per b.
// U = C R3 C R2 C R1  =>  U^dag = R1^d C^d R2^d C^d R3^d C^d (apply left->right
// as: C^d, R3^d, C^d, R2^d, C^d, R1^d).
// CNOT chain dagger composed into ONE permutation pass.
// Per-qubit rotation dagger fused into one SU(2) matrix G = RY(-p0)RX(-p1)RZ(-p2):
//   g00 = e^{+i p2/2} (c0 c1 + i s0 s1),  g01 = e^{-i p2/2} (s0 c1 + i c0 s1)
//   g10 = -conj(g01), g11 = conj(g00)
// ---------------------------------------------------------------------------

__device__ __forceinline__ void apply_rot(float* re, float* im, int w,
                                          float g00r, float g00i,
                                          float g01r, float g01i) {
  const int str = 1 << (11 - w);
#pragma unroll
  for (int t = 0; t < 2; ++t) {
    int p  = threadIdx.x + t * 1024;           // pair id, 2048 pairs total
    int lo = p & (str - 1);
    int k0 = ((p ^ lo) << 1) | lo;             // (p & ~(str-1))*2 + lo
    int k1 = k0 + str;
    float ar = re[k0], ai = im[k0], br = re[k1], bi = im[k1];
    // a' = g00 a + g01 b
    re[k0] =  g00r*ar - g00i*ai + g01r*br - g01i*bi;
    im[k0] =  g00r*ai + g00i*ar + g01r*bi + g01i*br;
    // b' = -conj(g01) a + conj(g00) b
    re[k1] = -g01r*ar - g01i*ai + g00r*br + g00i*bi;
    im[k1] = -g01r*ai + g01i*ar + g00r*bi - g00i*br;
  }
  __syncthreads();
}

__global__ __launch_bounds__(1024) void qnn_prep(const float* __restrict__ params,
                                                 float* __restrict__ M) {
  __shared__ float re[DIM], im[DIM];
  const int tid  = threadIdx.x;
  const int bvec = blockIdx.x;                 // 0 or 1

  for (int k = tid; k < DIM; k += 1024) { re[k] = 0.f; im[k] = 0.f; }
  __syncthreads();
  if (tid == 0) re[bvec] = 1.0f;
  __syncthreads();

  for (int layer = 2; layer >= 0; --layer) {
    // ---- C^dagger: composed permutation, one pass -------------------------
    {
      float rr[4], ii[4];
#pragma unroll
      for (int t = 0; t < 4; ++t) {
        int m = tid + t * 1024;
        int s = m;
#pragma unroll
        for (int q = 0; q <= 10; ++q)          // apply f_0 first ... f_10 last
          s ^= ((s >> (11 - q)) & 1) << (10 - q);
        rr[t] = re[s]; ii[t] = im[s];
      }
      __syncthreads();
#pragma unroll
      for (int t = 0; t < 4; ++t) { re[tid + t*1024] = rr[t]; im[tid + t*1024] = ii[t]; }
      __syncthreads();
    }
    // ---- R_layer^dagger: fused per-qubit SU(2) ---------------------------
    for (int q = 0; q < NQ; ++q) {
      float p0 = params[(layer*NQ + q)*3 + 0];
      float p1 = params[(layer*NQ + q)*3 + 1];
      float p2 = params[(layer*NQ + q)*3 + 2];
      float s0, c0, s1, c1, sz, cz;
      __sincosf(0.5f*p0, &s0, &c0);
      __sincosf(0.5f*p1, &s1, &c1);
      __sincosf(0.5f*p2, &sz, &cz);
      float ur = c0*c1, ui = s0*s1;
      float wr = s0*c1, wi = c0*s1;
      float g00r = cz*ur - sz*ui, g00i = cz*ui + sz*ur;
      float g01r = cz*wr + sz*wi, g01i = cz*wi - sz*wr;
      apply_rot(re, im, q, g00r, g00i, g01r, g01i);
    }
  }

  // interleaved write: M[k] = (v0re, v0im, v1re, v1im)
  for (int k = tid; k < DIM; k += 1024) {
    M[4*k + 2*bvec + 0] = re[k];
    M[4*k + 2*bvec + 1] = im[k];
  }
}

// ---------------------------------------------------------------------------
// Kernel B: per batch element b:
//   a_v = sum_{i,j} M_v[i*64+j] * sL[i] * sR[j]   (v = 0,1; complex, no conj
//   needed since only |a|^2 is used), then out = [p0,p1]/(p0+p1).
// One wave = 4 batch elements; lane = j; lane l also holds sL[l], broadcast
// via __shfl in the i-loop.  M staged once per block into LDS (64 KB).
// ---------------------------------------------------------------------------

__global__ __launch_bounds__(256) void qnn_main(const float* __restrict__ x,
                                                const float* __restrict__ M,
                                                float* __restrict__ out,
                                                int nbatch) {
  __shared__ float4 Ms[DIM];
  const float4* Mg = (const float4*)M;
  for (int t = threadIdx.x; t < DIM; t += 256) Ms[t] = Mg[t];
  __syncthreads();

  const int lane   = threadIdx.x & 63;
  const int wave   = threadIdx.x >> 6;
  const int batch0 = blockIdx.x * 16 + wave * 4;

  float sLv[4], sRv[4];
#pragma unroll
  for (int b = 0; b < 4; ++b) {
    const float* xb = x + (size_t)(batch0 + b) * NQ;
    float sl = 1.f, sr = 1.f;
#pragma unroll
    for (int w = 0; w < 6; ++w) {              // wires 0..5 -> bit (5-w) of i
      float s, c; __sincosf(0.5f * xb[w], &s, &c);
      sl *= ((lane >> (5 - w)) & 1) ? s : c;
    }
#pragma unroll
    for (int w = 6; w < 12; ++w) {             // wires 6..11 -> bit (11-w) of j
      float s, c; __sincosf(0.5f * xb[w], &s, &c);
      sr *= ((lane >> (11 - w)) & 1) ? s : c;
    }
    sLv[b] = sl; sRv[b] = sr;
  }

  float acc[4][4];
#pragma unroll
  for (int b = 0; b < 4; ++b)
#pragma unroll
    for (int c = 0; c < 4; ++c) acc[b][c] = 0.f;

  for (int i = 0; i < 64; ++i) {
    float4 m = Ms[i * 64 + lane];
#pragma unroll
    for (int b = 0; b < 4; ++b) {
      float sv = __shfl(sLv[b], i) * sRv[b];
      acc[b][0] = fmaf(m.x, sv, acc[b][0]);
      acc[b][1] = fmaf(m.y, sv, acc[b][1]);
      acc[b][2] = fmaf(m.z, sv, acc[b][2]);
      acc[b][3] = fmaf(m.w, sv, acc[b][3]);
    }
  }

  // reduce over j (lanes)
#pragma unroll
  for (int off = 32; off > 0; off >>= 1)
#pragma unroll
    for (int b = 0; b < 4; ++b)
#pragma unroll
      for (int c = 0; c < 4; ++c)
        acc[b][c] += __shfl_xor(acc[b][c], off);

  if (lane == 0) {
#pragma unroll
    for (int b = 0; b < 4; ++b) {
      float p0 = acc[b][0]*acc[b][0] + acc[b][1]*acc[b][1];
      float p1 = acc[b][2]*acc[b][2] + acc[b][3]*acc[b][3];
      float inv = 1.0f / (p0 + p1);
      if (batch0 + b < nbatch)
        ((float2*)out)[batch0 + b] = make_float2(p0 * inv, p1 * inv);
    }
  }
}

extern "C" void kernel_launch(void* const* d_in, const int* in_sizes, int n_in,
                              void* d_out, int out_size, void* d_ws, size_t ws_size,
                              hipStream_t stream) {
  const float* x      = (const float*)d_in[0];
  const float* params = (const float*)d_in[1];
  float* out = (float*)d_out;
  float* M   = (float*)d_ws;                   // 4096 * 4 floats = 64 KB

  const int nbatch = in_sizes[0] / NQ;         // 8192
  qnn_prep<<<2, 1024, 0, stream>>>(params, M);
  qnn_main<<<(nbatch + 15) / 16, 256, 0, stream>>>(x, M, out, nbatch);
}

// Round 2
// 89.934 us; speedup vs baseline: 1.0711x; 1.0711x over previous
//
#include <hip/hip_runtime.h>
#include <math.h>

#define NQ  12
#define DIM 4096

// ===========================================================================
// Prep: v_b = U^dagger e_b for b in {0,1}; U = C R3 C R2 C R1.
// U^dag e_b applied as: C^d, R3^d, C^d, R2^d, C^d, R1^d.
// C^d on index: gather from s = suffix_xor(k). s fixes 0 and 1, so
// C^d e_b = e_b and R3^d e_b is a PRODUCT STATE -> direct closed-form init.
// Remaining: perm, R2^d, perm, R1^d.
//
// State layout (per block, one block per b): 256 threads x 16 complex regs.
//   k = tid*16 + c :  c bits [3:0] -> qubits 8..11 (register rotations)
//                     lane bits [5:0] = k[9:4] -> qubits 2..7 (shfl_xor)
//                     wave bits k[11:10] = tid bits 7,6 -> qubits 0,1 (LDS)
// Fused dagger gate per qubit: G = [[g00,g01],[-conj(g01),conj(g00)]].
// ===========================================================================

struct Gate { float g00r, g00i, g01r, g01i; };

__device__ __forceinline__ Gate make_gate(const float* __restrict__ params,
                                          int layer, int q) {
  float p0 = params[(layer*NQ + q)*3 + 0];
  float p1 = params[(layer*NQ + q)*3 + 1];
  float p2 = params[(layer*NQ + q)*3 + 2];
  float s0, c0, s1, c1, sz, cz;
  __sincosf(0.5f*p0, &s0, &c0);
  __sincosf(0.5f*p1, &s1, &c1);
  __sincosf(0.5f*p2, &sz, &cz);
  float ur = c0*c1, ui = s0*s1, wr = s0*c1, wi = c0*s1;
  Gate g;
  g.g00r = cz*ur - sz*ui;  g.g00i = cz*ui + sz*ur;
  g.g01r = cz*wr + sz*wi;  g.g01i = cz*wi - sz*wr;
  return g;
}

__device__ __forceinline__ void rot_reg(float re[16], float im[16], int rb, Gate g) {
#pragma unroll
  for (int c = 0; c < 16; ++c) {
    if (c & (1 << rb)) continue;
    int c1 = c | (1 << rb);
    float ar = re[c], ai = im[c], br = re[c1], bi = im[c1];
    re[c]  =  g.g00r*ar - g.g00i*ai + g.g01r*br - g.g01i*bi;
    im[c]  =  g.g00r*ai + g.g00i*ar + g.g01r*bi + g.g01i*br;
    re[c1] = -g.g01r*ar - g.g01i*ai + g.g00r*br + g.g00i*bi;
    im[c1] = -g.g01r*ai + g.g01i*ar + g.g00r*bi - g.g00i*br;
  }
}

// own coeff: bit? conj(g00) : g00 ; partner coeff: bit? -conj(g01) : g01
__device__ __forceinline__ void rot_lane(float re[16], float im[16], int mask,
                                         int lane, Gate g) {
  float sgn = (lane & mask) ? -1.f : 1.f;
  float ocr = g.g00r,     oci = sgn * g.g00i;
  float pcr = sgn * g.g01r, pci = g.g01i;
#pragma unroll
  for (int c = 0; c < 16; ++c) {
    float br = __shfl_xor(re[c], mask);
    float bi = __shfl_xor(im[c], mask);
    float ar = re[c], ai = im[c];
    re[c] = ocr*ar - oci*ai + pcr*br - pci*bi;
    im[c] = ocr*ai + oci*ar + pcr*bi + pci*br;
  }
}

__device__ __forceinline__ void rot_wave(float re[16], float im[16], int tmask,
                                         float4* buf, int tid, Gate g) {
#pragma unroll
  for (int h = 0; h < 8; ++h)
    buf[h*256 + tid] = make_float4(re[2*h], im[2*h], re[2*h+1], im[2*h+1]);
  __syncthreads();
  int ptid = tid ^ tmask;
  float sgn = (tid & tmask) ? -1.f : 1.f;
  float ocr = g.g00r,       oci = sgn * g.g00i;
  float pcr = sgn * g.g01r, pci = g.g01i;
#pragma unroll
  for (int h = 0; h < 8; ++h) {
    float4 p = buf[h*256 + ptid];
    float ar, ai;
    ar = re[2*h];   ai = im[2*h];
    re[2*h]   = ocr*ar - oci*ai + pcr*p.x - pci*p.y;
    im[2*h]   = ocr*ai + oci*ar + pcr*p.y + pci*p.x;
    ar = re[2*h+1]; ai = im[2*h+1];
    re[2*h+1] = ocr*ar - oci*ai + pcr*p.z - pci*p.w;
    im[2*h+1] = ocr*ai + oci*ar + pcr*p.w + pci*p.z;
  }
}

// perm: new[k] = old[s], s = suffix_xor(k).  LDS loc(k) = (k&15)*256 + (k>>4)
// (transposed so wave accesses are lane-consecutive).
__device__ __forceinline__ void perm_pass(float re[16], float im[16],
                                          float2* buf, int tid) {
#pragma unroll
  for (int c = 0; c < 16; ++c)
    buf[c*256 + tid] = make_float2(re[c], im[c]);
  __syncthreads();
#pragma unroll
  for (int c = 0; c < 16; ++c) {
    int k = tid*16 + c;
    int s = k; s ^= s >> 1; s ^= s >> 2; s ^= s >> 4; s ^= s >> 8;
    float2 v = buf[(s & 15)*256 + (s >> 4)];
    re[c] = v.x; im[c] = v.y;
  }
}

__device__ __forceinline__ void apply_layer(float re[16], float im[16],
                                            const float* __restrict__ params,
                                            int layer, int tid, int lane,
                                            float4* bufW1, float4* bufW0) {
  rot_reg (re, im, 0,        make_gate(params, layer, 11));
  rot_reg (re, im, 1,        make_gate(params, layer, 10));
  rot_reg (re, im, 2,        make_gate(params, layer,  9));
  rot_reg (re, im, 3,        make_gate(params, layer,  8));
  rot_lane(re, im, 1,  lane, make_gate(params, layer,  7));
  rot_lane(re, im, 2,  lane, make_gate(params, layer,  6));
  rot_lane(re, im, 4,  lane, make_gate(params, layer,  5));
  rot_lane(re, im, 8,  lane, make_gate(params, layer,  4));
  rot_lane(re, im, 16, lane, make_gate(params, layer,  3));
  rot_lane(re, im, 32, lane, make_gate(params, layer,  2));
  rot_wave(re, im, 64,  bufW1, tid, make_gate(params, layer, 1));
  rot_wave(re, im, 128, bufW0, tid, make_gate(params, layer, 0));
}

__global__ __launch_bounds__(256) void qnn_prep(const float* __restrict__ params,
                                                float* __restrict__ M) {
  __shared__ float4 bufA[2048];
  __shared__ float4 bufB[2048];
  const int tid  = threadIdx.x;
  const int lane = tid & 63;
  const int b    = blockIdx.x;                 // 0 or 1

  float re[16], im[16];

  // ---- init: state = R3^dagger e_b (product state; C^d e_b = e_b) --------
  {
    Gate G8  = make_gate(params, 2,  8);
    Gate G9  = make_gate(params, 2,  9);
    Gate G10 = make_gate(params, 2, 10);
    Gate G11 = make_gate(params, 2, 11);
    // column b_q of G: col0 = (g00, -conj(g01)); col1 = (g01, conj(g00))
    float Pr = 1.f, Pi = 0.f;
#pragma unroll
    for (int q = 0; q < 8; ++q) {              // qubits 0..7 <-> tid bits 7-q
      Gate g = make_gate(params, 2, q);
      int bit = (tid >> (7 - q)) & 1;
      float fr = bit ? -g.g01r : g.g00r;
      float fi = bit ?  g.g01i : g.g00i;
      float nr = Pr*fr - Pi*fi, ni = Pr*fi + Pi*fr;
      Pr = nr; Pi = ni;
    }
    // qubit 11 factor depends on b (b=1 selects column 1 there)
    float f11_0r = b ? G11.g01r : G11.g00r;
    float f11_0i = b ? G11.g01i : G11.g00i;
    float f11_1r = b ? G11.g00r : -G11.g01r;
    float f11_1i = b ? -G11.g00i : G11.g01i;
#pragma unroll
    for (int c = 0; c < 16; ++c) {
      float ar = Pr, ai = Pi, fr, fi, nr, ni;
      fr = (c & 8) ? -G8.g01r : G8.g00r;  fi = (c & 8) ? G8.g01i : G8.g00i;
      nr = ar*fr - ai*fi; ni = ar*fi + ai*fr; ar = nr; ai = ni;
      fr = (c & 4) ? -G9.g01r : G9.g00r;  fi = (c & 4) ? G9.g01i : G9.g00i;
      nr = ar*fr - ai*fi; ni = ar*fi + ai*fr; ar = nr; ai = ni;
      fr = (c & 2) ? -G10.g01r : G10.g00r; fi = (c & 2) ? G10.g01i : G10.g00i;
      nr = ar*fr - ai*fi; ni = ar*fi + ai*fr; ar = nr; ai = ni;
      fr = (c & 1) ? f11_1r : f11_0r;     fi = (c & 1) ? f11_1i : f11_0i;
      nr = ar*fr - ai*fi; ni = ar*fi + ai*fr;
      re[c] = nr; im[c] = ni;
    }
  }

  // ---- perm, R2^d, perm, R1^d  (LDS buffers alternated, 1 barrier/pass) --
  perm_pass(re, im, (float2*)bufA, tid);
  apply_layer(re, im, params, 1, tid, lane, bufB, bufA);
  perm_pass(re, im, (float2*)bufB, tid);
  apply_layer(re, im, params, 0, tid, lane, bufA, bufB);

  // ---- write out: M[k] = (v0re, v0im, v1re, v1im) ------------------------
#pragma unroll
  for (int c = 0; c < 16; ++c) {
    int k = tid*16 + c;
    ((float2*)M)[2*k + b] = make_float2(re[c], im[c]);
  }
}

// ===========================================================================
// Main: per batch element, a_v = sum_{i,j} M_v[i*64+j] sL[i] sR[j]; output
// normalized |a_0|^2, |a_1|^2.  One wave = 4 batch elements, lane = j.
// ===========================================================================

__global__ __launch_bounds__(256) void qnn_main(const float* __restrict__ x,
                                                const float* __restrict__ M,
                                                float* __restrict__ out,
                                                int nbatch) {
  __shared__ float4 Ms[DIM];
  const float4* Mg = (const float4*)M;
  for (int t = threadIdx.x; t < DIM; t += 256) Ms[t] = Mg[t];
  __syncthreads();

  const int lane   = threadIdx.x & 63;
  const int wave   = threadIdx.x >> 6;
  const int batch0 = blockIdx.x * 16 + wave * 4;

  float sLv[4], sRv[4];
#pragma unroll
  for (int b = 0; b < 4; ++b) {
    const float* xb = x + (size_t)(batch0 + b) * NQ;
    float sl = 1.f, sr = 1.f;
#pragma unroll
    for (int w = 0; w < 6; ++w) {
      float s, c; __sincosf(0.5f * xb[w], &s, &c);
      sl *= ((lane >> (5 - w)) & 1) ? s : c;
    }
#pragma unroll
    for (int w = 6; w < 12; ++w) {
      float s, c; __sincosf(0.5f * xb[w], &s, &c);
      sr *= ((lane >> (11 - w)) & 1) ? s : c;
    }
    sLv[b] = sl; sRv[b] = sr;
  }

  float acc[4][4];
#pragma unroll
  for (int b = 0; b < 4; ++b)
#pragma unroll
    for (int c = 0; c < 4; ++c) acc[b][c] = 0.f;

  for (int i = 0; i < 64; ++i) {
    float4 m = Ms[i * 64 + lane];
#pragma unroll
    for (int b = 0; b < 4; ++b) {
      float sv = __shfl(sLv[b], i) * sRv[b];
      acc[b][0] = fmaf(m.x, sv, acc[b][0]);
      acc[b][1] = fmaf(m.y, sv, acc[b][1]);
      acc[b][2] = fmaf(m.z, sv, acc[b][2]);
      acc[b][3] = fmaf(m.w, sv, acc[b][3]);
    }
  }

#pragma unroll
  for (int off = 32; off > 0; off >>= 1)
#pragma unroll
    for (int b = 0; b < 4; ++b)
#pragma unroll
      for (int c = 0; c < 4; ++c)
        acc[b][c] += __shfl_xor(acc[b][c], off);

  if (lane == 0) {
#pragma unroll
    for (int b = 0; b < 4; ++b) {
      float p0 = acc[b][0]*acc[b][0] + acc[b][1]*acc[b][1];
      float p1 = acc[b][2]*acc[b][2] + acc[b][3]*acc[b][3];
      float inv = 1.0f / (p0 + p1);
      if (batch0 + b < nbatch)
        ((float2*)out)[batch0 + b] = make_float2(p0 * inv, p1 * inv);
    }
  }
}

extern "C" void kernel_launch(void* const* d_in, const int* in_sizes, int n_in,
                              void* d_out, int out_size, void* d_ws, size_t ws_size,
                              hipStream_t stream) {
  const float* x      = (const float*)d_in[0];
  const float* params = (const float*)d_in[1];
  float* out = (float*)d_out;
  float* M   = (float*)d_ws;                   // 4096 * 4 floats = 64 KB

  const int nbatch = in_sizes[0] / NQ;         // 8192
  qnn_prep<<<2, 256, 0, stream>>>(params, M);
  qnn_main<<<(nbatch + 15) / 16, 256, 0, stream>>>(x, M, out, nbatch);
}